// Round 8
// baseline (232.071 us; speedup 1.0000x reference)
//
#include <hip/hip_runtime.h>
#include <hip/hip_bf16.h>

constexpr int L = 8192;          // nodes
constexpr int H = 4;             // heads (both layers)

typedef __attribute__((ext_vector_type(8))) short bf16x8;
typedef __attribute__((ext_vector_type(8))) unsigned short u16x8;
typedef __attribute__((ext_vector_type(4))) float f32x4;

static __device__ __forceinline__ float lrelu(float e) {
  return e > 0.f ? e : 0.2f * e;
}
static __device__ __forceinline__ float b2f(unsigned short s) {
  return __uint_as_float(((unsigned)s) << 16);
}
static __device__ __forceinline__ unsigned short f2b(float f) {
  __hip_bfloat16 h = __float2bfloat16(f);
  return *reinterpret_cast<unsigned short*>(&h);
}

// ========== merged: LDS-tiled transposes (blocks 0..991) + elementwise tail ====
__global__ __launch_bounds__(256) void conv_combo(
    const float* __restrict__ seq, const float* __restrict__ W1,
    const float* __restrict__ W2, const float* __restrict__ Wg1,
    const float* __restrict__ Wg2, const float* __restrict__ fcW,
    const float* __restrict__ outW, const int* __restrict__ ei,
    const float* __restrict__ as1, const float* __restrict__ ad1,
    const float* __restrict__ as2, const float* __restrict__ ad2,
    int E, int Etot,
    __hip_bfloat16* __restrict__ xb, __hip_bfloat16* __restrict__ W1t,
    __hip_bfloat16* __restrict__ W2t, __hip_bfloat16* __restrict__ Wg1t,
    __hip_bfloat16* __restrict__ Wg2t, float* __restrict__ fcWt,
    float* __restrict__ outWt, float* __restrict__ wa2,
    int* __restrict__ deg, int* __restrict__ rank) {
  __shared__ float tile[32][33];
  if (blockIdx.x < 992) {
    int b = blockIdx.x;
    const float* src; void* dst; bool obf16; int K, N, Kout, kt, nt;
    if (b < 256)               { src = W2;  dst = W2t;  obf16 = true;  K = 1024; N = 256; Kout = 1024; nt = b & 7;  kt = b >> 3; }
    else if ((b -= 256) < 64)  { src = Wg1; dst = Wg1t; obf16 = true;  K = 256;  N = 256; Kout = 256;  nt = b & 7;  kt = b >> 3; }
    else if ((b -= 64) < 128)  { src = Wg2; dst = Wg2t; obf16 = true;  K = 256;  N = 512; Kout = 256;  nt = b & 15; kt = b >> 4; }
    else if ((b -= 128) < 256) { src = fcW; dst = fcWt; obf16 = false; K = 512;  N = 512; Kout = 512;  nt = b & 15; kt = b >> 4; }
    else if ((b -= 256) < 256) { src = outW;dst = outWt;obf16 = false; K = 512;  N = 489; Kout = 512;  nt = b & 15; kt = b >> 4; }
    else { b -= 256;             src = W1;  dst = W1t;  obf16 = true;  K = 26;   N = 1024;Kout = 32;   nt = b;      kt = 0; }
    int t = threadIdx.x;
    int lr = t >> 3, lc4 = (t & 7) * 4;
    int gk = kt * 32 + lr, gn = nt * 32 + lc4;
    float4 v = {0.f, 0.f, 0.f, 0.f};
    if (gk < K) {
      const float* p = &src[(size_t)gk * N + gn];
      v.x = (gn + 0 < N) ? p[0] : 0.f;
      v.y = (gn + 1 < N) ? p[1] : 0.f;
      v.z = (gn + 2 < N) ? p[2] : 0.f;
      v.w = (gn + 3 < N) ? p[3] : 0.f;
    }
    tile[lr][lc4 + 0] = v.x; tile[lr][lc4 + 1] = v.y;
    tile[lr][lc4 + 2] = v.z; tile[lr][lc4 + 3] = v.w;
    __syncthreads();
    int on = nt * 32 + lr, ok = kt * 32 + lc4;
    if (on >= N || ok >= Kout) return;
    float o0 = tile[lc4 + 0][lr], o1 = tile[lc4 + 1][lr];
    float o2 = tile[lc4 + 2][lr], o3 = tile[lc4 + 3][lr];
    if (obf16) {
      ushort4 u = {f2b(o0), f2b(o1), f2b(o2), f2b(o3)};
      *(ushort4*)&((__hip_bfloat16*)dst)[(size_t)on * Kout + ok] = u;
    } else {
      float4 u = {o0, o1, o2, o3};
      *(float4*)&((float*)dst)[(size_t)on * Kout + ok] = u;
    }
    return;
  }
  int i = (blockIdx.x - 992) * 256 + threadIdx.x;
  if (i < 262144) { int r = i >> 5, k = i & 31;
    xb[i] = __float2bfloat16(k < 26 ? seq[r * 26 + k] : 0.f); return; }
  i -= 262144;
  if (i < 2048) {  // Wg1t extension rows 256..263: wa1[k][o] in bf16
    int k = i >> 3, o = i & 7, h = o & 3;
    const float* av = (o < 4) ? as1 : ad1;
    float s = 0.f;
    for (int c = 0; c < 64; c++) s += Wg1[k * 256 + h * 64 + c] * av[h * 64 + c];
    Wg1t[(size_t)(256 + o) * 256 + k] = __float2bfloat16(s); return; }
  i -= 2048;
  if (i < 2048) {  // wa2 f32 (for gat1's fused a_sd2 epilogue)
    int k = i >> 3, o = i & 7, h = o & 3;
    const float* av = (o < 4) ? as2 : ad2;
    float s = 0.f;
    for (int c = 0; c < 128; c++) s += Wg2[k * 512 + h * 128 + c] * av[h * 128 + c];
    wa2[i] = s; return; }
  i -= 2048;
  if (i < 14336) {  // Wg1t zero rows 264..319
    ((__hip_bfloat16*)Wg1t)[(size_t)264 * 256 + i] = __float2bfloat16(0.f); return; }
  i -= 14336;
  if (i < Etot) {
    int dst = (i < E) ? ei[E + i] : (i - E);
    rank[i] = atomicAdd(&deg[dst], 1);
  }
}

// ============ bf16 MFMA GEMM: C = op(A[M,K] @ Bt[*,K]^T), 128x64 tile =========
template<int BK, bool RELU, bool ASD>
__global__ __launch_bounds__(256) void gemm_big(
    const __hip_bfloat16* __restrict__ A, const __hip_bfloat16* __restrict__ Bt,
    __hip_bfloat16* __restrict__ C, float* __restrict__ asd,
    int M, int N, int K) {
  __shared__ __align__(16) short As[128][BK + 8];
  __shared__ __align__(16) short Bs[64][BK + 8];
  int tid = threadIdx.x;
  int m0 = blockIdx.y * 128, n0 = blockIdx.x * 64;
  int w = tid >> 6, lane = tid & 63;
  int wm = (w >> 1) * 64, wn = (w & 1) * 32;
  f32x4 acc[4][2] = {};
  for (int k0 = 0; k0 < K; k0 += BK) {
    if constexpr (BK == 64) {
#pragma unroll
      for (int i = 0; i < 4; i++) {
        int ch = i * 256 + tid; int r = ch >> 3, kg = ch & 7;
        *(bf16x8*)&As[r][kg * 8] = *(const bf16x8*)&A[(size_t)(m0 + r) * K + k0 + kg * 8];
      }
#pragma unroll
      for (int i = 0; i < 2; i++) {
        int ch = i * 256 + tid; int r = ch >> 3, kg = ch & 7;
        *(bf16x8*)&Bs[r][kg * 8] = *(const bf16x8*)&Bt[(size_t)(n0 + r) * K + k0 + kg * 8];
      }
    } else {  // BK == 32
#pragma unroll
      for (int i = 0; i < 2; i++) {
        int ch = i * 256 + tid; int r = ch >> 2, kg = ch & 3;
        *(bf16x8*)&As[r][kg * 8] = *(const bf16x8*)&A[(size_t)(m0 + r) * K + k0 + kg * 8];
      }
      { int r = tid >> 2, kg = tid & 3;
        *(bf16x8*)&Bs[r][kg * 8] = *(const bf16x8*)&Bt[(size_t)(n0 + r) * K + k0 + kg * 8]; }
    }
    __syncthreads();
    int kk = (lane >> 4) * 8;
#pragma unroll
    for (int ks = 0; ks < BK / 32; ks++) {
      bf16x8 af[4], bfr[2];
#pragma unroll
      for (int m = 0; m < 4; m++)
        af[m] = *(const bf16x8*)&As[wm + m * 16 + (lane & 15)][ks * 32 + kk];
#pragma unroll
      for (int n = 0; n < 2; n++)
        bfr[n] = *(const bf16x8*)&Bs[wn + n * 16 + (lane & 15)][ks * 32 + kk];
#pragma unroll
      for (int m = 0; m < 4; m++)
#pragma unroll
        for (int n = 0; n < 2; n++)
          acc[m][n] = __builtin_amdgcn_mfma_f32_16x16x32_bf16(af[m], bfr[n], acc[m][n], 0, 0, 0);
    }
    __syncthreads();
  }
#pragma unroll
  for (int m = 0; m < 4; m++) {
#pragma unroll
    for (int n = 0; n < 2; n++) {
      int col = n0 + wn + n * 16 + (lane & 15);
#pragma unroll
      for (int j = 0; j < 4; j++) {
        int row = m0 + wm + m * 16 + (lane >> 4) * 4 + j;
        float v = acc[m][n][j];
        if (RELU) v = fmaxf(v, 0.f);
        if (!ASD) {
          C[(size_t)row * N + col] = __float2bfloat16(v);
        } else {
          if (col < N) C[(size_t)row * N + col] = __float2bfloat16(v);
          else if (col < N + 8) asd[(size_t)row * 8 + (col - N)] = v;
        }
      }
    }
  }
}

// ================= CSR build: shuffle-based scan (1 barrier) =================
__global__ __launch_bounds__(1024) void scan_deg(const int* __restrict__ deg,
                                                 int* __restrict__ row_start,
                                                 float* __restrict__ pooled) {
  __shared__ int wsum[16];
  int t = threadIdx.x;
  if (t < 512) pooled[t] = 0.f;
  int lane = t & 63, w = t >> 6;
  int local[8];
  int sum = 0;
#pragma unroll
  for (int j = 0; j < 8; j++) { local[j] = deg[t * 8 + j]; sum += local[j]; }
  int v = sum;
#pragma unroll
  for (int off = 1; off < 64; off <<= 1) {
    int u = __shfl_up(v, off);
    if (lane >= off) v += u;
  }
  if (lane == 63) wsum[w] = v;
  __syncthreads();
  int woff = 0;
  for (int i = 0; i < w; i++) woff += wsum[i];
  int base = woff + v - sum;   // exclusive prefix
#pragma unroll
  for (int j = 0; j < 8; j++) { row_start[t * 8 + j] = base; base += local[j]; }
  if (t == 1023) row_start[L] = base;
}

// atomic-free scatter using precomputed ranks
__global__ void scatter_edges(const int* __restrict__ ei, int E, int Etot,
                              const int* __restrict__ row_start,
                              const int* __restrict__ rank, int* __restrict__ csr_src) {
  int e = blockIdx.x * blockDim.x + threadIdx.x;
  if (e >= Etot) return;
  int srcv, dstv;
  if (e < E) { srcv = ei[e]; dstv = ei[E + e]; } else { srcv = dstv = e - E; }
  csr_src[row_start[dstv] + rank[e]] = srcv;
}

// ========= per-edge alpha (unnormalized, bf16x4) + per-node inv (f32x4) ========
// one wave per node; lanes stride the incoming edges. alpha write is coalesced.
__global__ __launch_bounds__(256) void calc_alpha(
    const float* __restrict__ a_sd, const int* __restrict__ row_start,
    const int* __restrict__ csr_src, unsigned short* __restrict__ alpha,
    float* __restrict__ inv4) {
  int wid = threadIdx.x >> 6, lane = threadIdx.x & 63;
  int n = blockIdx.x * 4 + wid;
  int rs = row_start[n], re = row_start[n + 1];
  float4 ad4 = *(const float4*)&a_sd[(size_t)n * 8 + 4];
  float dp[4] = {0.f, 0.f, 0.f, 0.f};
  for (int base = rs + lane; base < re; base += 64) {
    int src = csr_src[base];
    float4 as4 = *(const float4*)&a_sd[(size_t)src * 8];
    float w0 = __expf(lrelu(as4.x + ad4.x));
    float w1 = __expf(lrelu(as4.y + ad4.y));
    float w2 = __expf(lrelu(as4.z + ad4.z));
    float w3 = __expf(lrelu(as4.w + ad4.w));
    dp[0] += w0; dp[1] += w1; dp[2] += w2; dp[3] += w3;
    ushort4 wv = {f2b(w0), f2b(w1), f2b(w2), f2b(w3)};
    *(ushort4*)&alpha[(size_t)base * 4] = wv;
  }
#pragma unroll
  for (int off = 32; off > 0; off >>= 1) {
#pragma unroll
    for (int h = 0; h < 4; h++) dp[h] += __shfl_xor(dp[h], off);
  }
  if (lane == 0) {
    float4 iv = {1.f / (dp[0] + 1e-16f), 1.f / (dp[1] + 1e-16f),
                 1.f / (dp[2] + 1e-16f), 1.f / (dp[3] + 1e-16f)};
    *(float4*)&inv4[(size_t)n * 4] = iv;
  }
}

// ====== gather+aggregate with precomputed alpha; chunk-pipelined; 1 wave/node ==
// PHASES: channel-phase split (blockIdx.y) so per-phase gathered footprint
// fits a 4MB per-XCD L2. ASD2: layer-1 also emits a_sd2 = relu_out1 @ wa2.
template<int C, int PHASES, bool ASD2>
__global__ __launch_bounds__(128) void gat_fused(
    const __hip_bfloat16* __restrict__ hfeat,
    const unsigned short* __restrict__ alpha, const float* __restrict__ inv4,
    const int* __restrict__ row_start, const int* __restrict__ csr_src,
    const float* __restrict__ bias, __hip_bfloat16* __restrict__ out,
    const float* __restrict__ wa2, float* __restrict__ a_sd2) {
  constexpr int HC = 4 * C;
  constexpr int CP = HC / PHASES;       // channels this phase (always 256)
  constexpr int BATCH = 16;             // in-flight row gathers
  static_assert(CP == 256, "phase width must be 256");
  int wid = threadIdx.x >> 6, lane = threadIdx.x & 63;
  int n = blockIdx.x * 2 + wid;
  int c0 = blockIdx.y * CP + lane * 4;
  int hh = c0 / C;
  int rs = row_start[n], re = row_start[n + 1];
  float4 iv4 = *(const float4*)&inv4[(size_t)n * 4];
  float bv[4];
#pragma unroll
  for (int k = 0; k < 4; k++) bv[k] = bias[c0 + k];

  __shared__ float s_w[2][64][4];   // per-wave alpha staging (2KB)
  float acc[4] = {0.f, 0.f, 0.f, 0.f};
  const unsigned short* hbase = (const unsigned short*)hfeat;

  // prologue: chunk-0 csr + alpha (both coalesced, independent)
  int base = rs;
  int cnt = min(64, re - rs);
  int srcv = 0;
  ushort4 av4 = {0, 0, 0, 0};
  if (lane < cnt) {
    srcv = csr_src[rs + lane];
    av4 = *(const ushort4*)&alpha[(size_t)(rs + lane) * 4];
  }

  while (base < re) {
    float4 wv = {b2f(av4.x), b2f(av4.y), b2f(av4.z), b2f(av4.w)};
    *(float4*)&s_w[wid][lane][0] = wv;
    // within-wave LDS write->read ordering (cross-wave sync illegal here)
    asm volatile("s_waitcnt lgkmcnt(0)" ::: "memory");
    int cur_src = srcv;
    int cur_cnt = cnt;
    // prefetch next chunk's csr + alpha (independent coalesced streams)
    int nbase = base + 64;
    bool have_next = nbase < re;
    cnt = min(64, re - nbase);
    srcv = 0;
    ushort4 nav4 = {0, 0, 0, 0};
    if (have_next && lane < cnt) {
      srcv = csr_src[nbase + lane];
      nav4 = *(const ushort4*)&alpha[(size_t)(nbase + lane) * 4];
    }

    int j = 0;
    for (; j + BATCH <= cur_cnt; j += BATCH) {
      int srs[BATCH];
#pragma unroll
      for (int k = 0; k < BATCH; k++) srs[k] = __builtin_amdgcn_readlane(cur_src, j + k);
      ushort4 v[BATCH];
#pragma unroll
      for (int k = 0; k < BATCH; k++)
        v[k] = *(const ushort4*)&hbase[(size_t)srs[k] * HC + c0];
#pragma unroll
      for (int k = 0; k < BATCH; k++) {
        float av = s_w[wid][j + k][hh];
        acc[0] = fmaf(av, b2f(v[k].x), acc[0]);
        acc[1] = fmaf(av, b2f(v[k].y), acc[1]);
        acc[2] = fmaf(av, b2f(v[k].z), acc[2]);
        acc[3] = fmaf(av, b2f(v[k].w), acc[3]);
      }
    }
    for (; j < cur_cnt; j++) {
      int sr = __builtin_amdgcn_readlane(cur_src, j);
      float av = s_w[wid][j][hh];
      ushort4 v = *(const ushort4*)&hbase[(size_t)sr * HC + c0];
      acc[0] = fmaf(av, b2f(v.x), acc[0]);
      acc[1] = fmaf(av, b2f(v.y), acc[1]);
      acc[2] = fmaf(av, b2f(v.z), acc[2]);
      acc[3] = fmaf(av, b2f(v.w), acc[3]);
    }
    av4 = nav4;
    base = nbase;
  }

  float inv = hh == 0 ? iv4.x : hh == 1 ? iv4.y : hh == 2 ? iv4.z : iv4.w;

  // ---- epilogue ----
#pragma unroll
  for (int k = 0; k < 4; k++)
    acc[k] = fmaxf(fmaf(acc[k], inv, bv[k]), 0.f);
  ushort4 ov = {f2b(acc[0]), f2b(acc[1]), f2b(acc[2]), f2b(acc[3])};
  *(ushort4*)((unsigned short*)out + (size_t)n * HC + c0) = ov;

  // ---- fused a_sd2 = relu_out1[n] @ wa2 (layer-1 instance only) ----
  if constexpr (ASD2) {
    float p[8] = {};
#pragma unroll
    for (int q = 0; q < 4; q++) {
      const float* wr = &wa2[(size_t)(c0 + q) * 8];
#pragma unroll
      for (int o = 0; o < 8; o++) p[o] = fmaf(acc[q], wr[o], p[o]);
    }
#pragma unroll
    for (int off = 32; off > 0; off >>= 1) {
#pragma unroll
      for (int o = 0; o < 8; o++) p[o] += __shfl_xor(p[o], off);
    }
    if (lane == 0) {
      float4 p0 = {p[0], p[1], p[2], p[3]};
      float4 p1 = {p[4], p[5], p[6], p[7]};
      *(float4*)&a_sd2[(size_t)n * 8 + 0] = p0;
      *(float4*)&a_sd2[(size_t)n * 8 + 4] = p1;
    }
  }
}

// ================= pooled column sum (bf16 in, f32 atomic out) =================
__global__ __launch_bounds__(512) void col_sum_bf16(const __hip_bfloat16* __restrict__ x,
                                                    float* __restrict__ pooled) {
  int t = threadIdx.x;
  float acc = 0.f;
  for (int r = blockIdx.x; r < L; r += 64)
    acc += b2f(*(const unsigned short*)&x[(size_t)r * 512 + t]);
  atomicAdd(&pooled[t], acc);
}

// ================= FC head (pre-transposed f32 weights) =================
__global__ __launch_bounds__(256) void fc1(const float* __restrict__ pooled,
                                           const float* __restrict__ Wt,
                                           const float* __restrict__ b,
                                           float* __restrict__ out) {
  __shared__ float pv[512];
  __shared__ float red[256];
  int t = threadIdx.x;
  pv[t] = pooled[t]; pv[t + 256] = pooled[t + 256];
  __syncthreads();
  int ol = t >> 4;
  int o = blockIdx.x * 16 + ol;
  int ks = (t & 15) * 32;
  float p = 0.f;
  const float* wr = &Wt[(size_t)o * 512 + ks];
#pragma unroll
  for (int kk = 0; kk < 32; kk++) p = fmaf(pv[ks + kk], wr[kk], p);
  red[t] = p;
  __syncthreads();
  if ((t & 15) == 0) {
    float s2 = 0.f;
#pragma unroll
    for (int i = 0; i < 16; i++) s2 += red[ol * 16 + i];
    out[o] = fmaxf(s2 + b[o], 0.f);
  }
}

__global__ __launch_bounds__(256) void fc2(const float* __restrict__ h,
                                           const float* __restrict__ Wt,
                                           const float* __restrict__ outb,
                                           float* __restrict__ out) {
  __shared__ float pv[512];
  __shared__ float red[256];
  int t = threadIdx.x;
  pv[t] = h[t]; pv[t + 256] = h[t + 256];
  __syncthreads();
  int ol = t >> 4;
  int o = blockIdx.x * 16 + ol;
  int ks = (t & 15) * 32;
  float p = 0.f;
  const float* wr = &Wt[(size_t)o * 512 + ks];
#pragma unroll
  for (int kk = 0; kk < 32; kk++) p = fmaf(pv[ks + kk], wr[kk], p);
  red[t] = p;
  __syncthreads();
  if ((t & 15) == 0 && o < 489) {
    float s2 = 0.f;
#pragma unroll
    for (int i = 0; i < 16; i++) s2 += red[ol * 16 + i];
    out[o] = s2 + outb[o];
  }
}

extern "C" void kernel_launch(void* const* d_in, const int* in_sizes, int n_in,
                              void* d_out, int out_size, void* d_ws, size_t ws_size,
                              hipStream_t stream) {
  const float* seq   = (const float*)d_in[0];
  const int*   ei    = (const int*)d_in[1];
  const float* W1    = (const float*)d_in[2];
  const float* W2    = (const float*)d_in[3];
  const float* Wg1   = (const float*)d_in[4];
  const float* asrc1 = (const float*)d_in[5];
  const float* adst1 = (const float*)d_in[6];
  const float* b1    = (const float*)d_in[7];
  const float* Wg2   = (const float*)d_in[8];
  const float* asrc2 = (const float*)d_in[9];
  const float* adst2 = (const float*)d_in[10];
  const float* b2    = (const float*)d_in[11];
  const float* fcW   = (const float*)d_in[12];
  const float* fcb   = (const float*)d_in[13];
  const float* outW  = (const float*)d_in[14];
  const float* outb  = (const float*)d_in[15];
  float* outp = (float*)d_out;

  const int E = in_sizes[1] / 2;      // 524288
  const int Etot = E + L;             // + self loops

  // ---- workspace layout ----
  char* ws = (char*)d_ws;
  __hip_bfloat16* mlp1 = (__hip_bfloat16*)(ws + 0);           // [L,1024] 16MB (dead after gemm2)
  __hip_bfloat16* out2 = (__hip_bfloat16*)(ws + 0);           // [L,512] 8MB
  unsigned short* alpha = (unsigned short*)(ws + (8u << 20)); // [Etot][4] bf16 4.3MB (after mlp1 dead)
  __hip_bfloat16* h2   = (__hip_bfloat16*)(ws + (16u << 20)); // [L,512] 8MB
  __hip_bfloat16* x0   = (__hip_bfloat16*)(ws + (24u << 20)); // [L,256] 4MB
  __hip_bfloat16* h1   = (__hip_bfloat16*)(ws + (28u << 20)); // [L,256] 4MB
  __hip_bfloat16* out1 = (__hip_bfloat16*)(ws + (32u << 20)); // [L,256] 4MB
  size_t off = (36u << 20);
  __hip_bfloat16* xb   = (__hip_bfloat16*)(ws + off); off += (size_t)L * 32 * 2;
  __hip_bfloat16* W1t  = (__hip_bfloat16*)(ws + off); off += (size_t)1024 * 32 * 2;
  __hip_bfloat16* W2t  = (__hip_bfloat16*)(ws + off); off += (size_t)256 * 1024 * 2;
  __hip_bfloat16* Wg1t = (__hip_bfloat16*)(ws + off); off += (size_t)320 * 256 * 2;  // extended
  __hip_bfloat16* Wg2t = (__hip_bfloat16*)(ws + off); off += (size_t)512 * 256 * 2;
  float* fcWt  = (float*)(ws + off); off += (size_t)512 * 512 * 4;
  float* outWt = (float*)(ws + off); off += (size_t)512 * 512 * 4;
  int* csr_src = (int*)(ws + off); off += (size_t)Etot * 4;
  int* rank    = (int*)(ws + off); off += (size_t)Etot * 4;
  off = (off + 255) & ~(size_t)255;
  int* row_start = (int*)(ws + off); off += (size_t)(L + 1) * 4;
  off = (off + 255) & ~(size_t)255;
  int* deg    = (int*)(ws + off); off += (size_t)L * 4;
  float* a_sd1 = (float*)(ws + off); off += (size_t)L * 8 * 4;
  float* a_sd2 = (float*)(ws + off); off += (size_t)L * 8 * 4;
  float* inv1 = (float*)(ws + off); off += (size_t)L * 4 * 4;
  float* inv2 = (float*)(ws + off); off += (size_t)L * 4 * 4;
  float* wa2 = (float*)(ws + off); off += 2048 * 4;
  float* pooled = (float*)(ws + off); off += 512 * 4;
  float* hbuf   = (float*)(ws + off); off += 512 * 4;

  // ---- zero deg ----
  hipMemsetAsync(deg, 0, (size_t)L * 4, stream);

  // ---- merged transposes + conversions + wa + degree/rank ----
  int convN = 262144 + 2048 + 2048 + 14336 + Etot;
  int convB = (convN + 255) / 256;
  conv_combo<<<992 + convB, 256, 0, stream>>>(
      seq, W1, W2, Wg1, Wg2, fcW, outW, ei, asrc1, adst1, asrc2, adst2, E, Etot,
      xb, W1t, W2t, Wg1t, Wg2t, fcWt, outWt, wa2, deg, rank);

  // ---- CSR ----
  scan_deg<<<1, 1024, 0, stream>>>(deg, row_start, pooled);
  scatter_edges<<<(Etot + 255) / 256, 256, 0, stream>>>(ei, E, Etot, row_start, rank, csr_src);

  // ---- input MLP ----
  gemm_big<32, true, false><<<dim3(16, 64), 256, 0, stream>>>(xb, W1t, mlp1, nullptr, L, 1024, 32);
  gemm_big<64, false, false><<<dim3(4, 64), 256, 0, stream>>>(mlp1, W2t, x0, nullptr, L, 256, 1024);

  // ---- GAT layer 1 (C=64): h1 GEMM also emits a_sd1 via extended Wg1t ----
  gemm_big<64, false, true><<<dim3(5, 64), 256, 0, stream>>>(x0, Wg1t, h1, a_sd1, L, 256, 256);
  calc_alpha<<<2048, 256, 0, stream>>>(a_sd1, row_start, csr_src, alpha, inv1);
  gat_fused<64, 1, true><<<dim3(4096, 1), 128, 0, stream>>>(h1, alpha, inv1, row_start, csr_src, b1, out1, wa2, a_sd2);

  // ---- GAT layer 2 (C=128), channel-phase-split gather ----
  gemm_big<64, false, false><<<dim3(8, 64), 256, 0, stream>>>(out1, Wg2t, h2, nullptr, L, 512, 256);
  calc_alpha<<<2048, 256, 0, stream>>>(a_sd2, row_start, csr_src, alpha, inv2);
  gat_fused<128, 2, false><<<dim3(4096, 2), 128, 0, stream>>>(h2, alpha, inv2, row_start, csr_src, b2, out2, nullptr, nullptr);

  // ---- pool + FC head ----
  col_sum_bf16<<<64, 512, 0, stream>>>(out2, pooled);
  fc1<<<32, 256, 0, stream>>>(pooled, fcWt, fcb, hbuf);
  fc2<<<31, 256, 0, stream>>>(hbuf, outWt, outb, outp);
}

// Round 9
// 221.688 us; speedup vs baseline: 1.0468x; 1.0468x over previous
//
#include <hip/hip_runtime.h>
#include <hip/hip_bf16.h>

constexpr int L = 8192;          // nodes
constexpr int H = 4;             // heads (both layers)

typedef __attribute__((ext_vector_type(8))) short bf16x8;
typedef __attribute__((ext_vector_type(8))) unsigned short u16x8;
typedef __attribute__((ext_vector_type(4))) float f32x4;

#if defined(__has_builtin)
#  if __has_builtin(__builtin_amdgcn_fdot2_f32_bf16)
#    define HAVE_DOT2 1
#  endif
#endif
#ifndef HAVE_DOT2
#  define HAVE_DOT2 0
#endif
#if HAVE_DOT2
typedef __attribute__((ext_vector_type(2))) __bf16 bfx2;
#endif

static __device__ __forceinline__ float lrelu(float e) {
  return e > 0.f ? e : 0.2f * e;
}
static __device__ __forceinline__ float b2f(unsigned short s) {
  return __uint_as_float(((unsigned)s) << 16);
}
static __device__ __forceinline__ unsigned short f2b(float f) {
  __hip_bfloat16 h = __float2bfloat16(f);
  return *reinterpret_cast<unsigned short*>(&h);
}

// per-edge channel-pair accumulate: hv[p] holds channels (2p,2p+1) as packed
// bf16; m.x = (alpha,0), m.y = (0,alpha) packed bf16 masks.
template<int PAIRS>
static __device__ __forceinline__ void edge_fma(const unsigned* hv, uint2 m, float* acc) {
#if HAVE_DOT2
#pragma unroll
  for (int p = 0; p < PAIRS; p++) {
    acc[2 * p]     = __builtin_amdgcn_fdot2_f32_bf16(
        __builtin_bit_cast(bfx2, hv[p]), __builtin_bit_cast(bfx2, m.x), acc[2 * p], false);
    acc[2 * p + 1] = __builtin_amdgcn_fdot2_f32_bf16(
        __builtin_bit_cast(bfx2, hv[p]), __builtin_bit_cast(bfx2, m.y), acc[2 * p + 1], false);
  }
#else
  float af = b2f((unsigned short)(m.x & 0xffffu));
#pragma unroll
  for (int p = 0; p < PAIRS; p++) {
    acc[2 * p]     = fmaf(af, b2f((unsigned short)(hv[p] & 0xffffu)), acc[2 * p]);
    acc[2 * p + 1] = fmaf(af, b2f((unsigned short)(hv[p] >> 16)), acc[2 * p + 1]);
  }
#endif
}

// ========== merged: LDS-tiled transposes (blocks 0..991) + elementwise tail ====
__global__ __launch_bounds__(256) void conv_combo(
    const float* __restrict__ seq, const float* __restrict__ W1,
    const float* __restrict__ W2, const float* __restrict__ Wg1,
    const float* __restrict__ Wg2, const float* __restrict__ fcW,
    const float* __restrict__ outW, const int* __restrict__ ei,
    const float* __restrict__ as1, const float* __restrict__ ad1,
    const float* __restrict__ as2, const float* __restrict__ ad2,
    int E, int Etot,
    __hip_bfloat16* __restrict__ xb, __hip_bfloat16* __restrict__ W1t,
    __hip_bfloat16* __restrict__ W2t, __hip_bfloat16* __restrict__ Wg1t,
    __hip_bfloat16* __restrict__ Wg2t, float* __restrict__ fcWt,
    float* __restrict__ outWt, float* __restrict__ wa2,
    int* __restrict__ deg, int* __restrict__ rank) {
  __shared__ float tile[32][33];
  if (blockIdx.x < 992) {
    int b = blockIdx.x;
    const float* src; void* dst; bool obf16; int K, N, Kout, kt, nt;
    if (b < 256)               { src = W2;  dst = W2t;  obf16 = true;  K = 1024; N = 256; Kout = 1024; nt = b & 7;  kt = b >> 3; }
    else if ((b -= 256) < 64)  { src = Wg1; dst = Wg1t; obf16 = true;  K = 256;  N = 256; Kout = 256;  nt = b & 7;  kt = b >> 3; }
    else if ((b -= 64) < 128)  { src = Wg2; dst = Wg2t; obf16 = true;  K = 256;  N = 512; Kout = 256;  nt = b & 15; kt = b >> 4; }
    else if ((b -= 128) < 256) { src = fcW; dst = fcWt; obf16 = false; K = 512;  N = 512; Kout = 512;  nt = b & 15; kt = b >> 4; }
    else if ((b -= 256) < 256) { src = outW;dst = outWt;obf16 = false; K = 512;  N = 489; Kout = 512;  nt = b & 15; kt = b >> 4; }
    else { b -= 256;             src = W1;  dst = W1t;  obf16 = true;  K = 26;   N = 1024;Kout = 32;   nt = b;      kt = 0; }
    int t = threadIdx.x;
    int lr = t >> 3, lc4 = (t & 7) * 4;
    int gk = kt * 32 + lr, gn = nt * 32 + lc4;
    float4 v = {0.f, 0.f, 0.f, 0.f};
    if (gk < K) {
      const float* p = &src[(size_t)gk * N + gn];
      v.x = (gn + 0 < N) ? p[0] : 0.f;
      v.y = (gn + 1 < N) ? p[1] : 0.f;
      v.z = (gn + 2 < N) ? p[2] : 0.f;
      v.w = (gn + 3 < N) ? p[3] : 0.f;
    }
    tile[lr][lc4 + 0] = v.x; tile[lr][lc4 + 1] = v.y;
    tile[lr][lc4 + 2] = v.z; tile[lr][lc4 + 3] = v.w;
    __syncthreads();
    int on = nt * 32 + lr, ok = kt * 32 + lc4;
    if (on >= N || ok >= Kout) return;
    float o0 = tile[lc4 + 0][lr], o1 = tile[lc4 + 1][lr];
    float o2 = tile[lc4 + 2][lr], o3 = tile[lc4 + 3][lr];
    if (obf16) {
      ushort4 u = {f2b(o0), f2b(o1), f2b(o2), f2b(o3)};
      *(ushort4*)&((__hip_bfloat16*)dst)[(size_t)on * Kout + ok] = u;
    } else {
      float4 u = {o0, o1, o2, o3};
      *(float4*)&((float*)dst)[(size_t)on * Kout + ok] = u;
    }
    return;
  }
  int i = (blockIdx.x - 992) * 256 + threadIdx.x;
  if (i < 262144) { int r = i >> 5, k = i & 31;
    xb[i] = __float2bfloat16(k < 26 ? seq[r * 26 + k] : 0.f); return; }
  i -= 262144;
  if (i < 2048) {  // Wg1t extension rows 256..263: wa1[k][o] in bf16
    int k = i >> 3, o = i & 7, h = o & 3;
    const float* av = (o < 4) ? as1 : ad1;
    float s = 0.f;
    for (int c = 0; c < 64; c++) s += Wg1[k * 256 + h * 64 + c] * av[h * 64 + c];
    Wg1t[(size_t)(256 + o) * 256 + k] = __float2bfloat16(s); return; }
  i -= 2048;
  if (i < 2048) {  // wa2 f32 (for gat1's fused a_sd2 epilogue)
    int k = i >> 3, o = i & 7, h = o & 3;
    const float* av = (o < 4) ? as2 : ad2;
    float s = 0.f;
    for (int c = 0; c < 128; c++) s += Wg2[k * 512 + h * 128 + c] * av[h * 128 + c];
    wa2[i] = s; return; }
  i -= 2048;
  if (i < 14336) {  // Wg1t zero rows 264..319
    ((__hip_bfloat16*)Wg1t)[(size_t)264 * 256 + i] = __float2bfloat16(0.f); return; }
  i -= 14336;
  if (i < Etot) {
    int dst = (i < E) ? ei[E + i] : (i - E);
    rank[i] = atomicAdd(&deg[dst], 1);
  }
}

// ============ bf16 MFMA GEMM: C = op(A[M,K] @ Bt[*,K]^T), 128x64 tile =========
template<int BK, bool RELU, bool ASD>
__global__ __launch_bounds__(256) void gemm_big(
    const __hip_bfloat16* __restrict__ A, const __hip_bfloat16* __restrict__ Bt,
    __hip_bfloat16* __restrict__ C, float* __restrict__ asd,
    int M, int N, int K) {
  __shared__ __align__(16) short As[128][BK + 8];
  __shared__ __align__(16) short Bs[64][BK + 8];
  int tid = threadIdx.x;
  int m0 = blockIdx.y * 128, n0 = blockIdx.x * 64;
  int w = tid >> 6, lane = tid & 63;
  int wm = (w >> 1) * 64, wn = (w & 1) * 32;
  f32x4 acc[4][2] = {};
  for (int k0 = 0; k0 < K; k0 += BK) {
    if constexpr (BK == 64) {
#pragma unroll
      for (int i = 0; i < 4; i++) {
        int ch = i * 256 + tid; int r = ch >> 3, kg = ch & 7;
        *(bf16x8*)&As[r][kg * 8] = *(const bf16x8*)&A[(size_t)(m0 + r) * K + k0 + kg * 8];
      }
#pragma unroll
      for (int i = 0; i < 2; i++) {
        int ch = i * 256 + tid; int r = ch >> 3, kg = ch & 7;
        *(bf16x8*)&Bs[r][kg * 8] = *(const bf16x8*)&Bt[(size_t)(n0 + r) * K + k0 + kg * 8];
      }
    } else {  // BK == 32
#pragma unroll
      for (int i = 0; i < 2; i++) {
        int ch = i * 256 + tid; int r = ch >> 2, kg = ch & 3;
        *(bf16x8*)&As[r][kg * 8] = *(const bf16x8*)&A[(size_t)(m0 + r) * K + k0 + kg * 8];
      }
      { int r = tid >> 2, kg = tid & 3;
        *(bf16x8*)&Bs[r][kg * 8] = *(const bf16x8*)&Bt[(size_t)(n0 + r) * K + k0 + kg * 8]; }
    }
    __syncthreads();
    int kk = (lane >> 4) * 8;
#pragma unroll
    for (int ks = 0; ks < BK / 32; ks++) {
      bf16x8 af[4], bfr[2];
#pragma unroll
      for (int m = 0; m < 4; m++)
        af[m] = *(const bf16x8*)&As[wm + m * 16 + (lane & 15)][ks * 32 + kk];
#pragma unroll
      for (int n = 0; n < 2; n++)
        bfr[n] = *(const bf16x8*)&Bs[wn + n * 16 + (lane & 15)][ks * 32 + kk];
#pragma unroll
      for (int m = 0; m < 4; m++)
#pragma unroll
        for (int n = 0; n < 2; n++)
          acc[m][n] = __builtin_amdgcn_mfma_f32_16x16x32_bf16(af[m], bfr[n], acc[m][n], 0, 0, 0);
    }
    __syncthreads();
  }
#pragma unroll
  for (int m = 0; m < 4; m++) {
#pragma unroll
    for (int n = 0; n < 2; n++) {
      int col = n0 + wn + n * 16 + (lane & 15);
#pragma unroll
      for (int j = 0; j < 4; j++) {
        int row = m0 + wm + m * 16 + (lane >> 4) * 4 + j;
        float v = acc[m][n][j];
        if (RELU) v = fmaxf(v, 0.f);
        if (!ASD) {
          C[(size_t)row * N + col] = __float2bfloat16(v);
        } else {
          if (col < N) C[(size_t)row * N + col] = __float2bfloat16(v);
          else if (col < N + 8) asd[(size_t)row * 8 + (col - N)] = v;
        }
      }
    }
  }
}

// ================= CSR build: shuffle-based scan (1 barrier) =================
__global__ __launch_bounds__(1024) void scan_deg(const int* __restrict__ deg,
                                                 int* __restrict__ row_start,
                                                 float* __restrict__ pooled) {
  __shared__ int wsum[16];
  int t = threadIdx.x;
  if (t < 512) pooled[t] = 0.f;
  int lane = t & 63, w = t >> 6;
  int local[8];
  int sum = 0;
#pragma unroll
  for (int j = 0; j < 8; j++) { local[j] = deg[t * 8 + j]; sum += local[j]; }
  int v = sum;
#pragma unroll
  for (int off = 1; off < 64; off <<= 1) {
    int u = __shfl_up(v, off);
    if (lane >= off) v += u;
  }
  if (lane == 63) wsum[w] = v;
  __syncthreads();
  int woff = 0;
  for (int i = 0; i < w; i++) woff += wsum[i];
  int base = woff + v - sum;   // exclusive prefix
#pragma unroll
  for (int j = 0; j < 8; j++) { row_start[t * 8 + j] = base; base += local[j]; }
  if (t == 1023) row_start[L] = base;
}

// atomic-free scatter using precomputed ranks
__global__ void scatter_edges(const int* __restrict__ ei, int E, int Etot,
                              const int* __restrict__ row_start,
                              const int* __restrict__ rank, int* __restrict__ csr_src) {
  int e = blockIdx.x * blockDim.x + threadIdx.x;
  if (e >= Etot) return;
  int srcv, dstv;
  if (e < E) { srcv = ei[e]; dstv = ei[E + e]; } else { srcv = dstv = e - E; }
  csr_src[row_start[dstv] + rank[e]] = srcv;
}

// ====== fused single-sweep softmax+aggregate; full-width gather + dot2 =========
// acc = sum_j exp(e_j)*h[src_j] (unnormalized) + denom; divide at end.
// Per-chunk (lane-parallel, cheap): csr+a_sd loads, exp, denominator adds,
// expand alpha to (a,0)/(0,a) bf16x2 masks in LDS. Consume loop (per-edge):
// readlane -> SGPR base, ds_read_b64 mask, full-row gather, PAIRS*2 dot2.
// ASD2: layer-1 instance also emits a_sd2[n][8] = relu_out1[n] @ wa2.
template<int C, bool ASD2>
__global__ __launch_bounds__(128) void gat_fused(
    const __hip_bfloat16* __restrict__ hfeat, const float* __restrict__ a_sd,
    const int* __restrict__ row_start, const int* __restrict__ csr_src,
    const float* __restrict__ bias, __hip_bfloat16* __restrict__ out,
    const float* __restrict__ wa2, float* __restrict__ a_sd2) {
  constexpr int HC = 4 * C;
  constexpr int VEC = HC / 64;      // 4 (C=64) or 8 (C=128) channels per lane
  constexpr int PAIRS = VEC / 2;
  constexpr int BATCH = 8;          // in-flight row gathers
  int wid = threadIdx.x >> 6, lane = threadIdx.x & 63;
  int n = blockIdx.x * 2 + wid;
  int c0 = lane * VEC;
  int hh = lane >> 4;               // == c0 / C for both layer configs
  int rs = row_start[n], re = row_start[n + 1];
  float4 ad4 = *(const float4*)&a_sd[(size_t)n * 8 + 4];

  __shared__ __align__(16) uint2 s_m[2][64][4];   // expanded alpha masks (4KB)
  float dp[4] = {0.f, 0.f, 0.f, 0.f};
  float acc[VEC] = {};
  const unsigned short* hbase = (const unsigned short*)hfeat;

  // prologue: chunk-0 csr + a_sd
  int base = rs;
  int cnt = min(64, re - rs);
  int srcv = 0;
  float4 as4 = {0.f, 0.f, 0.f, 0.f};
  if (lane < cnt) {
    srcv = csr_src[rs + lane];
    as4 = *(const float4*)&a_sd[(size_t)srcv * 8];
  }

  while (base < re) {
    float w0 = 0.f, w1 = 0.f, w2 = 0.f, w3 = 0.f;
    if (lane < cnt) {
      w0 = __expf(lrelu(as4.x + ad4.x));
      w1 = __expf(lrelu(as4.y + ad4.y));
      w2 = __expf(lrelu(as4.z + ad4.z));
      w3 = __expf(lrelu(as4.w + ad4.w));
    }
    dp[0] += w0; dp[1] += w1; dp[2] += w2; dp[3] += w3;
    unsigned l0 = f2b(w0), l1 = f2b(w1), l2 = f2b(w2), l3 = f2b(w3);
    uint4 ma = {l0, l0 << 16, l1, l1 << 16};
    uint4 mb = {l2, l2 << 16, l3, l3 << 16};
    *(uint4*)&s_m[wid][lane][0] = ma;
    *(uint4*)&s_m[wid][lane][2] = mb;
    // within-wave LDS write->read ordering (cross-wave sync illegal here)
    asm volatile("s_waitcnt lgkmcnt(0)" ::: "memory");
    int cur_src = srcv;
    int cur_cnt = cnt;
    // prefetch next chunk's csr (independent coalesced load)
    int nbase = base + 64;
    bool have_next = nbase < re;
    cnt = min(64, re - nbase);
    srcv = 0;
    if (have_next && lane < cnt) srcv = csr_src[nbase + lane];
    float4 nas4 = {0.f, 0.f, 0.f, 0.f};
    bool did_asd = false;

    int j = 0;
    for (; j + BATCH <= cur_cnt; j += BATCH) {
      int srs[BATCH];
#pragma unroll
      for (int k = 0; k < BATCH; k++) srs[k] = __builtin_amdgcn_readlane(cur_src, j + k);
      unsigned hv[BATCH][PAIRS];
#pragma unroll
      for (int k = 0; k < BATCH; k++) {
        const unsigned short* hp = &hbase[(size_t)srs[k] * HC + c0];
        if constexpr (PAIRS == 4) *(uint4*)&hv[k][0] = *(const uint4*)hp;
        else                      *(uint2*)&hv[k][0] = *(const uint2*)hp;
      }
      if (j == 0 && have_next) {   // csr prefetch has landed by now; issue a_sd
        if (lane < cnt) nas4 = *(const float4*)&a_sd[(size_t)srcv * 8];
        did_asd = true;
      }
#pragma unroll
      for (int k = 0; k < BATCH; k++) {
        uint2 m = s_m[wid][j + k][hh];
        edge_fma<PAIRS>(hv[k], m, acc);
      }
    }
    if (have_next && !did_asd && lane < cnt)
      nas4 = *(const float4*)&a_sd[(size_t)srcv * 8];
    for (; j < cur_cnt; j++) {
      int sr = __builtin_amdgcn_readlane(cur_src, j);
      unsigned hv[PAIRS];
      const unsigned short* hp = &hbase[(size_t)sr * HC + c0];
      if constexpr (PAIRS == 4) *(uint4*)&hv[0] = *(const uint4*)hp;
      else                      *(uint2*)&hv[0] = *(const uint2*)hp;
      uint2 m = s_m[wid][j][hh];
      edge_fma<PAIRS>(hv, m, acc);
    }
    as4 = nas4;
    base = nbase;
  }

  // ---- denominator: butterfly-sum the 4 heads, select own head ----
#pragma unroll
  for (int off = 32; off > 0; off >>= 1) {
#pragma unroll
    for (int h = 0; h < 4; h++) dp[h] += __shfl_xor(dp[h], off);
  }
  float dsel = hh == 0 ? dp[0] : hh == 1 ? dp[1] : hh == 2 ? dp[2] : dp[3];
  float inv = 1.f / (dsel + 1e-16f);

  // ---- epilogue ----
#pragma unroll
  for (int k = 0; k < VEC; k++)
    acc[k] = fmaxf(fmaf(acc[k], inv, bias[c0 + k]), 0.f);
  unsigned short* op = (unsigned short*)out + (size_t)n * HC + c0;
  if constexpr (VEC == 8) {
    u16x8 ov;
#pragma unroll
    for (int k = 0; k < 8; k++) ov[k] = f2b(acc[k]);
    *(u16x8*)op = ov;
  } else {
    ushort4 ov = {f2b(acc[0]), f2b(acc[1]), f2b(acc[2]), f2b(acc[3])};
    *(ushort4*)op = ov;
  }

  // ---- fused a_sd2 = relu_out1[n] @ wa2 (layer-1 instance only) ----
  if constexpr (ASD2) {
    float p[8] = {};
#pragma unroll
    for (int q = 0; q < VEC; q++) {
      const float* wr = &wa2[(size_t)(c0 + q) * 8];
#pragma unroll
      for (int o = 0; o < 8; o++) p[o] = fmaf(acc[q], wr[o], p[o]);
    }
#pragma unroll
    for (int off = 32; off > 0; off >>= 1) {
#pragma unroll
      for (int o = 0; o < 8; o++) p[o] += __shfl_xor(p[o], off);
    }
    if (lane == 0) {
      float4 p0 = {p[0], p[1], p[2], p[3]};
      float4 p1 = {p[4], p[5], p[6], p[7]};
      *(float4*)&a_sd2[(size_t)n * 8 + 0] = p0;
      *(float4*)&a_sd2[(size_t)n * 8 + 4] = p1;
    }
  }
}

// ================= pooled column sum (bf16 in, f32 atomic out) =================
__global__ __launch_bounds__(512) void col_sum_bf16(const __hip_bfloat16* __restrict__ x,
                                                    float* __restrict__ pooled) {
  int t = threadIdx.x;
  float acc = 0.f;
  for (int r = blockIdx.x; r < L; r += 64)
    acc += b2f(*(const unsigned short*)&x[(size_t)r * 512 + t]);
  atomicAdd(&pooled[t], acc);
}

// ================= FC head (pre-transposed f32 weights) =================
__global__ __launch_bounds__(256) void fc1(const float* __restrict__ pooled,
                                           const float* __restrict__ Wt,
                                           const float* __restrict__ b,
                                           float* __restrict__ out) {
  __shared__ float pv[512];
  __shared__ float red[256];
  int t = threadIdx.x;
  pv[t] = pooled[t]; pv[t + 256] = pooled[t + 256];
  __syncthreads();
  int ol = t >> 4;
  int o = blockIdx.x * 16 + ol;
  int ks = (t & 15) * 32;
  float p = 0.f;
  const float* wr = &Wt[(size_t)o * 512 + ks];
#pragma unroll
  for (int kk = 0; kk < 32; kk++) p = fmaf(pv[ks + kk], wr[kk], p);
  red[t] = p;
  __syncthreads();
  if ((t & 15) == 0) {
    float s2 = 0.f;
#pragma unroll
    for (int i = 0; i < 16; i++) s2 += red[ol * 16 + i];
    out[o] = fmaxf(s2 + b[o], 0.f);
  }
}

__global__ __launch_bounds__(256) void fc2(const float* __restrict__ h,
                                           const float* __restrict__ Wt,
                                           const float* __restrict__ outb,
                                           float* __restrict__ out) {
  __shared__ float pv[512];
  __shared__ float red[256];
  int t = threadIdx.x;
  pv[t] = h[t]; pv[t + 256] = h[t + 256];
  __syncthreads();
  int ol = t >> 4;
  int o = blockIdx.x * 16 + ol;
  int ks = (t & 15) * 32;
  float p = 0.f;
  const float* wr = &Wt[(size_t)o * 512 + ks];
#pragma unroll
  for (int kk = 0; kk < 32; kk++) p = fmaf(pv[ks + kk], wr[kk], p);
  red[t] = p;
  __syncthreads();
  if ((t & 15) == 0 && o < 489) {
    float s2 = 0.f;
#pragma unroll
    for (int i = 0; i < 16; i++) s2 += red[ol * 16 + i];
    out[o] = s2 + outb[o];
  }
}

extern "C" void kernel_launch(void* const* d_in, const int* in_sizes, int n_in,
                              void* d_out, int out_size, void* d_ws, size_t ws_size,
                              hipStream_t stream) {
  const float* seq   = (const float*)d_in[0];
  const int*   ei    = (const int*)d_in[1];
  const float* W1    = (const float*)d_in[2];
  const float* W2    = (const float*)d_in[3];
  const float* Wg1   = (const float*)d_in[4];
  const float* asrc1 = (const float*)d_in[5];
  const float* adst1 = (const float*)d_in[6];
  const float* b1    = (const float*)d_in[7];
  const float* Wg2   = (const float*)d_in[8];
  const float* asrc2 = (const float*)d_in[9];
  const float* adst2 = (const float*)d_in[10];
  const float* b2    = (const float*)d_in[11];
  const float* fcW   = (const float*)d_in[12];
  const float* fcb   = (const float*)d_in[13];
  const float* outW  = (const float*)d_in[14];
  const float* outb  = (const float*)d_in[15];
  float* outp = (float*)d_out;

  const int E = in_sizes[1] / 2;      // 524288
  const int Etot = E + L;             // + self loops

  // ---- workspace layout ----
  char* ws = (char*)d_ws;
  __hip_bfloat16* mlp1 = (__hip_bfloat16*)(ws + 0);           // [L,1024] 16MB (dead after gemm2)
  __hip_bfloat16* out2 = (__hip_bfloat16*)(ws + 0);           // [L,512] 8MB
  __hip_bfloat16* h2   = (__hip_bfloat16*)(ws + (16u << 20)); // [L,512] 8MB
  __hip_bfloat16* x0   = (__hip_bfloat16*)(ws + (24u << 20)); // [L,256] 4MB
  __hip_bfloat16* h1   = (__hip_bfloat16*)(ws + (28u << 20)); // [L,256] 4MB
  __hip_bfloat16* out1 = (__hip_bfloat16*)(ws + (32u << 20)); // [L,256] 4MB
  size_t off = (36u << 20);
  __hip_bfloat16* xb   = (__hip_bfloat16*)(ws + off); off += (size_t)L * 32 * 2;
  __hip_bfloat16* W1t  = (__hip_bfloat16*)(ws + off); off += (size_t)1024 * 32 * 2;
  __hip_bfloat16* W2t  = (__hip_bfloat16*)(ws + off); off += (size_t)256 * 1024 * 2;
  __hip_bfloat16* Wg1t = (__hip_bfloat16*)(ws + off); off += (size_t)320 * 256 * 2;  // extended
  __hip_bfloat16* Wg2t = (__hip_bfloat16*)(ws + off); off += (size_t)512 * 256 * 2;
  float* fcWt  = (float*)(ws + off); off += (size_t)512 * 512 * 4;
  float* outWt = (float*)(ws + off); off += (size_t)512 * 512 * 4;
  int* csr_src = (int*)(ws + off); off += (size_t)Etot * 4;
  int* rank    = (int*)(ws + off); off += (size_t)Etot * 4;
  off = (off + 255) & ~(size_t)255;
  int* row_start = (int*)(ws + off); off += (size_t)(L + 1) * 4;
  off = (off + 255) & ~(size_t)255;
  int* deg    = (int*)(ws + off); off += (size_t)L * 4;
  float* a_sd1 = (float*)(ws + off); off += (size_t)L * 8 * 4;
  float* a_sd2 = (float*)(ws + off); off += (size_t)L * 8 * 4;
  float* wa2 = (float*)(ws + off); off += 2048 * 4;
  float* pooled = (float*)(ws + off); off += 512 * 4;
  float* hbuf   = (float*)(ws + off); off += 512 * 4;

  // ---- zero deg ----
  hipMemsetAsync(deg, 0, (size_t)L * 4, stream);

  // ---- merged transposes + conversions + wa + degree/rank ----
  int convN = 262144 + 2048 + 2048 + 14336 + Etot;
  int convB = (convN + 255) / 256;
  conv_combo<<<992 + convB, 256, 0, stream>>>(
      seq, W1, W2, Wg1, Wg2, fcW, outW, ei, asrc1, adst1, asrc2, adst2, E, Etot,
      xb, W1t, W2t, Wg1t, Wg2t, fcWt, outWt, wa2, deg, rank);

  // ---- CSR ----
  scan_deg<<<1, 1024, 0, stream>>>(deg, row_start, pooled);
  scatter_edges<<<(Etot + 255) / 256, 256, 0, stream>>>(ei, E, Etot, row_start, rank, csr_src);

  // ---- input MLP ----
  gemm_big<32, true, false><<<dim3(16, 64), 256, 0, stream>>>(xb, W1t, mlp1, nullptr, L, 1024, 32);
  gemm_big<64, false, false><<<dim3(4, 64), 256, 0, stream>>>(mlp1, W2t, x0, nullptr, L, 256, 1024);

  // ---- GAT layer 1 (C=64): h1 GEMM also emits a_sd1 via extended Wg1t ----
  gemm_big<64, false, true><<<dim3(5, 64), 256, 0, stream>>>(x0, Wg1t, h1, a_sd1, L, 256, 256);
  gat_fused<64, true><<<4096, 128, 0, stream>>>(h1, a_sd1, row_start, csr_src, b1, out1, wa2, a_sd2);

  // ---- GAT layer 2 (C=128): full-width single-pass gather ----
  gemm_big<64, false, false><<<dim3(8, 64), 256, 0, stream>>>(out1, Wg2t, h2, nullptr, L, 512, 256);
  gat_fused<128, false><<<4096, 128, 0, stream>>>(h2, a_sd2, row_start, csr_src, b2, out2, nullptr, nullptr);

  // ---- pool + FC head ----
  col_sum_bf16<<<64, 512, 0, stream>>>(out2, pooled);
  fc1<<<32, 256, 0, stream>>>(pooled, fcWt, fcb, hbuf);
  fc2<<<31, 256, 0, stream>>>(hbuf, outWt, outb, outp);
}

// Round 10
// 220.494 us; speedup vs baseline: 1.0525x; 1.0054x over previous
//
#include <hip/hip_runtime.h>
#include <hip/hip_bf16.h>

constexpr int L = 8192;          // nodes
constexpr int H = 4;             // heads (both layers)

typedef __attribute__((ext_vector_type(8))) short bf16x8;
typedef __attribute__((ext_vector_type(8))) unsigned short u16x8;
typedef __attribute__((ext_vector_type(4))) float f32x4;

#if defined(__has_builtin)
#  if __has_builtin(__builtin_amdgcn_fdot2_f32_bf16)
#    define HAVE_DOT2 1
#  endif
#endif
#ifndef HAVE_DOT2
#  define HAVE_DOT2 0
#endif
#if HAVE_DOT2
typedef __attribute__((ext_vector_type(2))) __bf16 bfx2;
#endif

static __device__ __forceinline__ float lrelu(float e) {
  return e > 0.f ? e : 0.2f * e;
}
static __device__ __forceinline__ float b2f(unsigned short s) {
  return __uint_as_float(((unsigned)s) << 16);
}
static __device__ __forceinline__ unsigned short f2b(float f) {
  __hip_bfloat16 h = __float2bfloat16(f);
  return *reinterpret_cast<unsigned short*>(&h);
}

// per-edge channel-pair accumulate: hv[p] holds channels (2p,2p+1) as packed
// bf16; m.x = (alpha,0), m.y = (0,alpha) packed bf16 masks.
template<int PAIRS>
static __device__ __forceinline__ void edge_fma(const unsigned* hv, uint2 m, float* acc) {
#if HAVE_DOT2
#pragma unroll
  for (int p = 0; p < PAIRS; p++) {
    acc[2 * p]     = __builtin_amdgcn_fdot2_f32_bf16(
        __builtin_bit_cast(bfx2, hv[p]), __builtin_bit_cast(bfx2, m.x), acc[2 * p], false);
    acc[2 * p + 1] = __builtin_amdgcn_fdot2_f32_bf16(
        __builtin_bit_cast(bfx2, hv[p]), __builtin_bit_cast(bfx2, m.y), acc[2 * p + 1], false);
  }
#else
  float af = b2f((unsigned short)(m.x & 0xffffu));
#pragma unroll
  for (int p = 0; p < PAIRS; p++) {
    acc[2 * p]     = fmaf(af, b2f((unsigned short)(hv[p] & 0xffffu)), acc[2 * p]);
    acc[2 * p + 1] = fmaf(af, b2f((unsigned short)(hv[p] >> 16)), acc[2 * p + 1]);
  }
#endif
}

// ========== merged: LDS-tiled transposes (blocks 0..991) + elementwise tail ====
__global__ __launch_bounds__(256) void conv_combo(
    const float* __restrict__ seq, const float* __restrict__ W1,
    const float* __restrict__ W2, const float* __restrict__ Wg1,
    const float* __restrict__ Wg2, const float* __restrict__ fcW,
    const float* __restrict__ outW, const int* __restrict__ ei,
    const float* __restrict__ as1, const float* __restrict__ ad1,
    const float* __restrict__ as2, const float* __restrict__ ad2,
    int E, int Etot,
    __hip_bfloat16* __restrict__ xb, __hip_bfloat16* __restrict__ W1t,
    __hip_bfloat16* __restrict__ W2t, __hip_bfloat16* __restrict__ Wg1t,
    __hip_bfloat16* __restrict__ Wg2t, float* __restrict__ fcWt,
    float* __restrict__ outWt, float* __restrict__ wa2,
    int* __restrict__ deg, int* __restrict__ rank) {
  __shared__ float tile[32][33];
  if (blockIdx.x < 992) {
    int b = blockIdx.x;
    const float* src; void* dst; bool obf16; int K, N, Kout, kt, nt;
    if (b < 256)               { src = W2;  dst = W2t;  obf16 = true;  K = 1024; N = 256; Kout = 1024; nt = b & 7;  kt = b >> 3; }
    else if ((b -= 256) < 64)  { src = Wg1; dst = Wg1t; obf16 = true;  K = 256;  N = 256; Kout = 256;  nt = b & 7;  kt = b >> 3; }
    else if ((b -= 64) < 128)  { src = Wg2; dst = Wg2t; obf16 = true;  K = 256;  N = 512; Kout = 256;  nt = b & 15; kt = b >> 4; }
    else if ((b -= 128) < 256) { src = fcW; dst = fcWt; obf16 = false; K = 512;  N = 512; Kout = 512;  nt = b & 15; kt = b >> 4; }
    else if ((b -= 256) < 256) { src = outW;dst = outWt;obf16 = false; K = 512;  N = 489; Kout = 512;  nt = b & 15; kt = b >> 4; }
    else { b -= 256;             src = W1;  dst = W1t;  obf16 = true;  K = 26;   N = 1024;Kout = 32;   nt = b;      kt = 0; }
    int t = threadIdx.x;
    int lr = t >> 3, lc4 = (t & 7) * 4;
    int gk = kt * 32 + lr, gn = nt * 32 + lc4;
    float4 v = {0.f, 0.f, 0.f, 0.f};
    if (gk < K) {
      const float* p = &src[(size_t)gk * N + gn];
      v.x = (gn + 0 < N) ? p[0] : 0.f;
      v.y = (gn + 1 < N) ? p[1] : 0.f;
      v.z = (gn + 2 < N) ? p[2] : 0.f;
      v.w = (gn + 3 < N) ? p[3] : 0.f;
    }
    tile[lr][lc4 + 0] = v.x; tile[lr][lc4 + 1] = v.y;
    tile[lr][lc4 + 2] = v.z; tile[lr][lc4 + 3] = v.w;
    __syncthreads();
    int on = nt * 32 + lr, ok = kt * 32 + lc4;
    if (on >= N || ok >= Kout) return;
    float o0 = tile[lc4 + 0][lr], o1 = tile[lc4 + 1][lr];
    float o2 = tile[lc4 + 2][lr], o3 = tile[lc4 + 3][lr];
    if (obf16) {
      ushort4 u = {f2b(o0), f2b(o1), f2b(o2), f2b(o3)};
      *(ushort4*)&((__hip_bfloat16*)dst)[(size_t)on * Kout + ok] = u;
    } else {
      float4 u = {o0, o1, o2, o3};
      *(float4*)&((float*)dst)[(size_t)on * Kout + ok] = u;
    }
    return;
  }
  int i = (blockIdx.x - 992) * 256 + threadIdx.x;
  if (i < 262144) { int r = i >> 5, k = i & 31;
    xb[i] = __float2bfloat16(k < 26 ? seq[r * 26 + k] : 0.f); return; }
  i -= 262144;
  if (i < 2048) {  // Wg1t extension rows 256..263: wa1[k][o] in bf16
    int k = i >> 3, o = i & 7, h = o & 3;
    const float* av = (o < 4) ? as1 : ad1;
    float s = 0.f;
    for (int c = 0; c < 64; c++) s += Wg1[k * 256 + h * 64 + c] * av[h * 64 + c];
    Wg1t[(size_t)(256 + o) * 256 + k] = __float2bfloat16(s); return; }
  i -= 2048;
  if (i < 2048) {  // wa2 f32 (for gat1's fused a_sd2 epilogue)
    int k = i >> 3, o = i & 7, h = o & 3;
    const float* av = (o < 4) ? as2 : ad2;
    float s = 0.f;
    for (int c = 0; c < 128; c++) s += Wg2[k * 512 + h * 128 + c] * av[h * 128 + c];
    wa2[i] = s; return; }
  i -= 2048;
  if (i < 14336) {  // Wg1t zero rows 264..319
    ((__hip_bfloat16*)Wg1t)[(size_t)264 * 256 + i] = __float2bfloat16(0.f); return; }
  i -= 14336;
  if (i < Etot) {
    int dst = (i < E) ? ei[E + i] : (i - E);
    rank[i] = atomicAdd(&deg[dst], 1);
  }
}

// ============ bf16 MFMA GEMM: C = op(A[M,K] @ Bt[*,K]^T), 128x64 tile =========
template<int BK, bool RELU, bool ASD>
__global__ __launch_bounds__(256) void gemm_big(
    const __hip_bfloat16* __restrict__ A, const __hip_bfloat16* __restrict__ Bt,
    __hip_bfloat16* __restrict__ C, float* __restrict__ asd,
    int M, int N, int K) {
  __shared__ __align__(16) short As[128][BK + 8];
  __shared__ __align__(16) short Bs[64][BK + 8];
  int tid = threadIdx.x;
  int m0 = blockIdx.y * 128, n0 = blockIdx.x * 64;
  int w = tid >> 6, lane = tid & 63;
  int wm = (w >> 1) * 64, wn = (w & 1) * 32;
  f32x4 acc[4][2] = {};
  for (int k0 = 0; k0 < K; k0 += BK) {
    if constexpr (BK == 64) {
#pragma unroll
      for (int i = 0; i < 4; i++) {
        int ch = i * 256 + tid; int r = ch >> 3, kg = ch & 7;
        *(bf16x8*)&As[r][kg * 8] = *(const bf16x8*)&A[(size_t)(m0 + r) * K + k0 + kg * 8];
      }
#pragma unroll
      for (int i = 0; i < 2; i++) {
        int ch = i * 256 + tid; int r = ch >> 3, kg = ch & 7;
        *(bf16x8*)&Bs[r][kg * 8] = *(const bf16x8*)&Bt[(size_t)(n0 + r) * K + k0 + kg * 8];
      }
    } else {  // BK == 32
#pragma unroll
      for (int i = 0; i < 2; i++) {
        int ch = i * 256 + tid; int r = ch >> 2, kg = ch & 3;
        *(bf16x8*)&As[r][kg * 8] = *(const bf16x8*)&A[(size_t)(m0 + r) * K + k0 + kg * 8];
      }
      { int r = tid >> 2, kg = tid & 3;
        *(bf16x8*)&Bs[r][kg * 8] = *(const bf16x8*)&Bt[(size_t)(n0 + r) * K + k0 + kg * 8]; }
    }
    __syncthreads();
    int kk = (lane >> 4) * 8;
#pragma unroll
    for (int ks = 0; ks < BK / 32; ks++) {
      bf16x8 af[4], bfr[2];
#pragma unroll
      for (int m = 0; m < 4; m++)
        af[m] = *(const bf16x8*)&As[wm + m * 16 + (lane & 15)][ks * 32 + kk];
#pragma unroll
      for (int n = 0; n < 2; n++)
        bfr[n] = *(const bf16x8*)&Bs[wn + n * 16 + (lane & 15)][ks * 32 + kk];
#pragma unroll
      for (int m = 0; m < 4; m++)
#pragma unroll
        for (int n = 0; n < 2; n++)
          acc[m][n] = __builtin_amdgcn_mfma_f32_16x16x32_bf16(af[m], bfr[n], acc[m][n], 0, 0, 0);
    }
    __syncthreads();
  }
#pragma unroll
  for (int m = 0; m < 4; m++) {
#pragma unroll
    for (int n = 0; n < 2; n++) {
      int col = n0 + wn + n * 16 + (lane & 15);
#pragma unroll
      for (int j = 0; j < 4; j++) {
        int row = m0 + wm + m * 16 + (lane >> 4) * 4 + j;
        float v = acc[m][n][j];
        if (RELU) v = fmaxf(v, 0.f);
        if (!ASD) {
          C[(size_t)row * N + col] = __float2bfloat16(v);
        } else {
          if (col < N) C[(size_t)row * N + col] = __float2bfloat16(v);
          else if (col < N + 8) asd[(size_t)row * 8 + (col - N)] = v;
        }
      }
    }
  }
}

// ================= CSR build: shuffle-based scan (1 barrier) =================
__global__ __launch_bounds__(1024) void scan_deg(const int* __restrict__ deg,
                                                 int* __restrict__ row_start,
                                                 float* __restrict__ pooled) {
  __shared__ int wsum[16];
  int t = threadIdx.x;
  if (t < 512) pooled[t] = 0.f;
  int lane = t & 63, w = t >> 6;
  int local[8];
  int sum = 0;
#pragma unroll
  for (int j = 0; j < 8; j++) { local[j] = deg[t * 8 + j]; sum += local[j]; }
  int v = sum;
#pragma unroll
  for (int off = 1; off < 64; off <<= 1) {
    int u = __shfl_up(v, off);
    if (lane >= off) v += u;
  }
  if (lane == 63) wsum[w] = v;
  __syncthreads();
  int woff = 0;
  for (int i = 0; i < w; i++) woff += wsum[i];
  int base = woff + v - sum;   // exclusive prefix
#pragma unroll
  for (int j = 0; j < 8; j++) { row_start[t * 8 + j] = base; base += local[j]; }
  if (t == 1023) row_start[L] = base;
}

// atomic-free scatter using precomputed ranks
__global__ void scatter_edges(const int* __restrict__ ei, int E, int Etot,
                              const int* __restrict__ row_start,
                              const int* __restrict__ rank, int* __restrict__ csr_src) {
  int e = blockIdx.x * blockDim.x + threadIdx.x;
  if (e >= Etot) return;
  int srcv, dstv;
  if (e < E) { srcv = ei[e]; dstv = ei[E + e]; } else { srcv = dstv = e - E; }
  csr_src[row_start[dstv] + rank[e]] = srcv;
}

// ====== fused single-sweep softmax+aggregate; phases (L2-resident) + dot2 ======
// acc = sum_j exp(e_j)*h[src_j] (unnormalized) + denom; divide at end.
// PHASES splits channels across blockIdx.y so the per-phase gathered table is
// <= 4MB (one XCD L2). VEC = HC/PHASES/64 = 4 channels/lane both layers.
// Consume loop per edge: readlane -> SGPR base, ds_read_b64 mask, 8B gather,
// 4 bf16-dot2. ASD2: layer-1 instance also emits a_sd2 = relu_out1 @ wa2.
template<int C, int PHASES, bool ASD2>
__global__ __launch_bounds__(128) void gat_fused(
    const __hip_bfloat16* __restrict__ hfeat, const float* __restrict__ a_sd,
    const int* __restrict__ row_start, const int* __restrict__ csr_src,
    const float* __restrict__ bias, __hip_bfloat16* __restrict__ out,
    const float* __restrict__ wa2, float* __restrict__ a_sd2) {
  constexpr int HC = 4 * C;
  constexpr int VEC = HC / PHASES / 64;   // 4 for both layers
  constexpr int PAIRS = VEC / 2;          // 2
  constexpr int BATCH = 12;               // in-flight 8B row gathers
  int wid = threadIdx.x >> 6, lane = threadIdx.x & 63;
  int n = blockIdx.x * 2 + wid;
  int c0 = blockIdx.y * 256 + lane * VEC;
  int hh = c0 / C;                        // head of this lane's channels
  int hl = hh & 3;
  int rs = row_start[n], re = row_start[n + 1];
  float4 ad4 = *(const float4*)&a_sd[(size_t)n * 8 + 4];

  __shared__ __align__(16) uint2 s_m[2][64][4];   // expanded alpha masks (4KB)
  float dp[4] = {0.f, 0.f, 0.f, 0.f};
  float acc[VEC] = {};
  const unsigned short* hbase = (const unsigned short*)hfeat;

  // prologue: chunk-0 csr + a_sd
  int base = rs;
  int cnt = min(64, re - rs);
  int srcv = 0;
  float4 as4 = {0.f, 0.f, 0.f, 0.f};
  if (lane < cnt) {
    srcv = csr_src[rs + lane];
    as4 = *(const float4*)&a_sd[(size_t)srcv * 8];
  }

  while (base < re) {
    float w0 = 0.f, w1 = 0.f, w2 = 0.f, w3 = 0.f;
    if (lane < cnt) {
      w0 = __expf(lrelu(as4.x + ad4.x));
      w1 = __expf(lrelu(as4.y + ad4.y));
      w2 = __expf(lrelu(as4.z + ad4.z));
      w3 = __expf(lrelu(as4.w + ad4.w));
    }
    dp[0] += w0; dp[1] += w1; dp[2] += w2; dp[3] += w3;
    unsigned l0 = f2b(w0), l1 = f2b(w1), l2 = f2b(w2), l3 = f2b(w3);
    uint4 ma = {l0, l0 << 16, l1, l1 << 16};
    uint4 mb = {l2, l2 << 16, l3, l3 << 16};
    *(uint4*)&s_m[wid][lane][0] = ma;
    *(uint4*)&s_m[wid][lane][2] = mb;
    // within-wave LDS write->read ordering (cross-wave sync illegal here)
    asm volatile("s_waitcnt lgkmcnt(0)" ::: "memory");
    int cur_src = srcv;
    int cur_cnt = cnt;
    // prefetch next chunk's csr (independent coalesced load)
    int nbase = base + 64;
    bool have_next = nbase < re;
    cnt = min(64, re - nbase);
    srcv = 0;
    if (have_next && lane < cnt) srcv = csr_src[nbase + lane];
    float4 nas4 = {0.f, 0.f, 0.f, 0.f};
    bool did_asd = false;

    int j = 0;
    for (; j + BATCH <= cur_cnt; j += BATCH) {
      int srs[BATCH];
#pragma unroll
      for (int k = 0; k < BATCH; k++) srs[k] = __builtin_amdgcn_readlane(cur_src, j + k);
      unsigned hv[BATCH][PAIRS];
#pragma unroll
      for (int k = 0; k < BATCH; k++) {
        const unsigned short* hp = &hbase[(size_t)srs[k] * HC + c0];
        *(uint2*)&hv[k][0] = *(const uint2*)hp;
      }
      if (j == 0 && have_next) {   // csr prefetch has landed by now; issue a_sd
        if (lane < cnt) nas4 = *(const float4*)&a_sd[(size_t)srcv * 8];
        did_asd = true;
      }
#pragma unroll
      for (int k = 0; k < BATCH; k++) {
        uint2 m = s_m[wid][j + k][hl];
        edge_fma<PAIRS>(hv[k], m, acc);
      }
    }
    if (have_next && !did_asd && lane < cnt)
      nas4 = *(const float4*)&a_sd[(size_t)srcv * 8];
    for (; j < cur_cnt; j++) {
      int sr = __builtin_amdgcn_readlane(cur_src, j);
      unsigned hv[PAIRS];
      const unsigned short* hp = &hbase[(size_t)sr * HC + c0];
      *(uint2*)&hv[0] = *(const uint2*)hp;
      uint2 m = s_m[wid][j][hl];
      edge_fma<PAIRS>(hv, m, acc);
    }
    as4 = nas4;
    base = nbase;
  }

  // ---- denominator: butterfly-sum the 4 heads, select own head ----
#pragma unroll
  for (int off = 32; off > 0; off >>= 1) {
#pragma unroll
    for (int h = 0; h < 4; h++) dp[h] += __shfl_xor(dp[h], off);
  }
  float dsel = hl == 0 ? dp[0] : hl == 1 ? dp[1] : hl == 2 ? dp[2] : dp[3];
  float inv = 1.f / (dsel + 1e-16f);

  // ---- epilogue ----
#pragma unroll
  for (int k = 0; k < VEC; k++)
    acc[k] = fmaxf(fmaf(acc[k], inv, bias[c0 + k]), 0.f);
  unsigned short* op = (unsigned short*)out + (size_t)n * HC + c0;
  ushort4 ov = {f2b(acc[0]), f2b(acc[1]), f2b(acc[2]), f2b(acc[3])};
  *(ushort4*)op = ov;

  // ---- fused a_sd2 = relu_out1[n] @ wa2 (layer-1 instance only) ----
  if constexpr (ASD2) {
    float p[8] = {};
#pragma unroll
    for (int q = 0; q < VEC; q++) {
      const float* wr = &wa2[(size_t)(c0 + q) * 8];
#pragma unroll
      for (int o = 0; o < 8; o++) p[o] = fmaf(acc[q], wr[o], p[o]);
    }
#pragma unroll
    for (int off = 32; off > 0; off >>= 1) {
#pragma unroll
      for (int o = 0; o < 8; o++) p[o] += __shfl_xor(p[o], off);
    }
    if (lane == 0) {
      float4 p0 = {p[0], p[1], p[2], p[3]};
      float4 p1 = {p[4], p[5], p[6], p[7]};
      *(float4*)&a_sd2[(size_t)n * 8 + 0] = p0;
      *(float4*)&a_sd2[(size_t)n * 8 + 4] = p1;
    }
  }
}

// ================= pooled column sum (bf16 in, f32 atomic out) =================
__global__ __launch_bounds__(512) void col_sum_bf16(const __hip_bfloat16* __restrict__ x,
                                                    float* __restrict__ pooled) {
  int t = threadIdx.x;
  float acc = 0.f;
  for (int r = blockIdx.x; r < L; r += 64)
    acc += b2f(*(const unsigned short*)&x[(size_t)r * 512 + t]);
  atomicAdd(&pooled[t], acc);
}

// ================= FC head (pre-transposed f32 weights) =================
__global__ __launch_bounds__(256) void fc1(const float* __restrict__ pooled,
                                           const float* __restrict__ Wt,
                                           const float* __restrict__ b,
                                           float* __restrict__ out) {
  __shared__ float pv[512];
  __shared__ float red[256];
  int t = threadIdx.x;
  pv[t] = pooled[t]; pv[t + 256] = pooled[t + 256];
  __syncthreads();
  int ol = t >> 4;
  int o = blockIdx.x * 16 + ol;
  int ks = (t & 15) * 32;
  float p = 0.f;
  const float* wr = &Wt[(size_t)o * 512 + ks];
#pragma unroll
  for (int kk = 0; kk < 32; kk++) p = fmaf(pv[ks + kk], wr[kk], p);
  red[t] = p;
  __syncthreads();
  if ((t & 15) == 0) {
    float s2 = 0.f;
#pragma unroll
    for (int i = 0; i < 16; i++) s2 += red[ol * 16 + i];
    out[o] = fmaxf(s2 + b[o], 0.f);
  }
}

__global__ __launch_bounds__(256) void fc2(const float* __restrict__ h,
                                           const float* __restrict__ Wt,
                                           const float* __restrict__ outb,
                                           float* __restrict__ out) {
  __shared__ float pv[512];
  __shared__ float red[256];
  int t = threadIdx.x;
  pv[t] = h[t]; pv[t + 256] = h[t + 256];
  __syncthreads();
  int ol = t >> 4;
  int o = blockIdx.x * 16 + ol;
  int ks = (t & 15) * 32;
  float p = 0.f;
  const float* wr = &Wt[(size_t)o * 512 + ks];
#pragma unroll
  for (int kk = 0; kk < 32; kk++) p = fmaf(pv[ks + kk], wr[kk], p);
  red[t] = p;
  __syncthreads();
  if ((t & 15) == 0 && o < 489) {
    float s2 = 0.f;
#pragma unroll
    for (int i = 0; i < 16; i++) s2 += red[ol * 16 + i];
    out[o] = s2 + outb[o];
  }
}

extern "C" void kernel_launch(void* const* d_in, const int* in_sizes, int n_in,
                              void* d_out, int out_size, void* d_ws, size_t ws_size,
                              hipStream_t stream) {
  const float* seq   = (const float*)d_in[0];
  const int*   ei    = (const int*)d_in[1];
  const float* W1    = (const float*)d_in[2];
  const float* W2    = (const float*)d_in[3];
  const float* Wg1   = (const float*)d_in[4];
  const float* asrc1 = (const float*)d_in[5];
  const float* adst1 = (const float*)d_in[6];
  const float* b1    = (const float*)d_in[7];
  const float* Wg2   = (const float*)d_in[8];
  const float* asrc2 = (const float*)d_in[9];
  const float* adst2 = (const float*)d_in[10];
  const float* b2    = (const float*)d_in[11];
  const float* fcW   = (const float*)d_in[12];
  const float* fcb   = (const float*)d_in[13];
  const float* outW  = (const float*)d_in[14];
  const float* outb  = (const float*)d_in[15];
  float* outp = (float*)d_out;

  const int E = in_sizes[1] / 2;      // 524288
  const int Etot = E + L;             // + self loops

  // ---- workspace layout ----
  char* ws = (char*)d_ws;
  __hip_bfloat16* mlp1 = (__hip_bfloat16*)(ws + 0);           // [L,1024] 16MB (dead after gemm2)
  __hip_bfloat16* out2 = (__hip_bfloat16*)(ws + 0);           // [L,512] 8MB
  __hip_bfloat16* h2   = (__hip_bfloat16*)(ws + (16u << 20)); // [L,512] 8MB
  __hip_bfloat16* x0   = (__hip_bfloat16*)(ws + (24u << 20)); // [L,256] 4MB
  __hip_bfloat16* h1   = (__hip_bfloat16*)(ws + (28u << 20)); // [L,256] 4MB
  __hip_bfloat16* out1 = (__hip_bfloat16*)(ws + (32u << 20)); // [L,256] 4MB
  size_t off = (36u << 20);
  __hip_bfloat16* xb   = (__hip_bfloat16*)(ws + off); off += (size_t)L * 32 * 2;
  __hip_bfloat16* W1t  = (__hip_bfloat16*)(ws + off); off += (size_t)1024 * 32 * 2;
  __hip_bfloat16* W2t  = (__hip_bfloat16*)(ws + off); off += (size_t)256 * 1024 * 2;
  __hip_bfloat16* Wg1t = (__hip_bfloat16*)(ws + off); off += (size_t)320 * 256 * 2;  // extended
  __hip_bfloat16* Wg2t = (__hip_bfloat16*)(ws + off); off += (size_t)512 * 256 * 2;
  float* fcWt  = (float*)(ws + off); off += (size_t)512 * 512 * 4;
  float* outWt = (float*)(ws + off); off += (size_t)512 * 512 * 4;
  int* csr_src = (int*)(ws + off); off += (size_t)Etot * 4;
  int* rank    = (int*)(ws + off); off += (size_t)Etot * 4;
  off = (off + 255) & ~(size_t)255;
  int* row_start = (int*)(ws + off); off += (size_t)(L + 1) * 4;
  off = (off + 255) & ~(size_t)255;
  int* deg    = (int*)(ws + off); off += (size_t)L * 4;
  float* a_sd1 = (float*)(ws + off); off += (size_t)L * 8 * 4;
  float* a_sd2 = (float*)(ws + off); off += (size_t)L * 8 * 4;
  float* wa2 = (float*)(ws + off); off += 2048 * 4;
  float* pooled = (float*)(ws + off); off += 512 * 4;
  float* hbuf   = (float*)(ws + off); off += 512 * 4;

  // ---- zero deg ----
  hipMemsetAsync(deg, 0, (size_t)L * 4, stream);

  // ---- merged transposes + conversions + wa + degree/rank ----
  int convN = 262144 + 2048 + 2048 + 14336 + Etot;
  int convB = (convN + 255) / 256;
  conv_combo<<<992 + convB, 256, 0, stream>>>(
      seq, W1, W2, Wg1, Wg2, fcW, outW, ei, asrc1, adst1, asrc2, adst2, E, Etot,
      xb, W1t, W2t, Wg1t, Wg2t, fcWt, outWt, wa2, deg, rank);

  // ---- CSR ----
  scan_deg<<<1, 1024, 0, stream>>>(deg, row_start, pooled);
  scatter_edges<<<(Etot + 255) / 256, 256, 0, stream>>>(ei, E, Etot, row_start, rank, csr_src);

  // ---- input MLP ----
  gemm_big<32, true, false><<<dim3(16, 64), 256, 0, stream>>>(xb, W1t, mlp1, nullptr, L, 1024, 32);
  gemm_big<64, false, false><<<dim3(4, 64), 256, 0, stream>>>(mlp1, W2t, x0, nullptr, L, 256, 1024);

  // ---- GAT layer 1 (C=64): h1 GEMM also emits a_sd1 via extended Wg1t ----
  gemm_big<64, false, true><<<dim3(5, 64), 256, 0, stream>>>(x0, Wg1t, h1, a_sd1, L, 256, 256);
  gat_fused<64, 1, true><<<dim3(4096, 1), 128, 0, stream>>>(h1, a_sd1, row_start, csr_src, b1, out1, wa2, a_sd2);

  // ---- GAT layer 2 (C=128): 2-phase L2-resident gather + dot2 consume ----
  gemm_big<64, false, false><<<dim3(8, 64), 256, 0, stream>>>(out1, Wg2t, h2, nullptr, L, 512, 256);
  gat_fused<128, 2, false><<<dim3(4096, 2), 128, 0, stream>>>(h2, a_sd2, row_start, csr_src, b2, out2, nullptr, nullptr);

  // ---- pool + FC head ----
  col_sum_bf16<<<64, 512, 0, stream>>>(out2, pooled);
  fc1<<<32, 256, 0, stream>>>(pooled, fcWt, fcb, hbuf);
  fc2<<<31, 256, 0, stream>>>(hbuf, outWt, outb, outp);
}